// Round 1
// baseline (5660.241 us; speedup 1.0000x reference)
//
#include <hip/hip_runtime.h>
#include <cmath>

#define NN 50000
#define EE 500000
#define GG 256
#define FA 92
#define FB 41
#define DD 64
#define HH 128
#define CQdim 16
#define NL 3
#define EPSBN 1e-5f

// ---------- helpers ----------
__device__ __forceinline__ float sp1(float x) {
    // stable softplus: max(x,0) + log1p(exp(-|x|))
    return fmaxf(x, 0.0f) + log1pf(expf(-fabsf(x)));
}
__device__ __forceinline__ float4 sp4(float4 v) {
    return make_float4(sp1(v.x), sp1(v.y), sp1(v.z), sp1(v.w));
}
__device__ __forceinline__ void atomAddF(float* p, float v) {
    unsafeAtomicAdd(p, v);   // hw global_atomic_add_f32 (avoid CAS loop)
}

// acc[i][c] += sum_k U[(r0+i)*LD + k] * W[k*64 + c0+c]
template<int K, int LD>
__device__ __forceinline__ void mm_tile(float4 acc[4], const float* __restrict__ Ubuf, int r0,
                                        const float* __restrict__ W, int c0)
{
#pragma unroll
    for (int k0 = 0; k0 < K; k0 += 4) {
        float4 w0 = *(const float4*)&W[(k0+0)*64 + c0];
        float4 w1 = *(const float4*)&W[(k0+1)*64 + c0];
        float4 w2 = *(const float4*)&W[(k0+2)*64 + c0];
        float4 w3 = *(const float4*)&W[(k0+3)*64 + c0];
#pragma unroll
        for (int i = 0; i < 4; ++i) {
            float4 u = *(const float4*)&Ubuf[(r0+i)*LD + k0];
            acc[i].x += u.x*w0.x + u.y*w1.x + u.z*w2.x + u.w*w3.x;
            acc[i].y += u.x*w0.y + u.y*w1.y + u.z*w2.y + u.w*w3.y;
            acc[i].z += u.x*w0.z + u.y*w1.z + u.z*w2.z + u.w*w3.z;
            acc[i].w += u.x*w0.w + u.y*w1.w + u.z*w2.w + u.w*w3.w;
        }
    }
}

// ---------- node embedding: h = concat(x, cf[batch]) @ W_atom + b_atom ----------
__global__ __launch_bounds__(256) void embed_node_kernel(
    const float* __restrict__ x, const int* __restrict__ batch,
    const float* __restrict__ charge, const float* __restrict__ Wc,
    const float* __restrict__ bc, const float* __restrict__ Wa,
    const float* __restrict__ ba, float* __restrict__ h)
{
    const int K = FA + CQdim; // 108
    __shared__ float sW[108*64];
    __shared__ float sX[64*108];
    for (int i = threadIdx.x; i < K*64; i += 256) sW[i] = Wa[i];
    const int fg = threadIdx.x & 15, ng = threadIdx.x >> 4, c0 = fg*4;
    for (int tb = blockIdx.x*64; tb < NN; tb += gridDim.x*64) {
        __syncthreads();
        for (int i = threadIdx.x; i < 64*K; i += 256) {
            int n = i / K, c = i % K;
            int node = tb + n;
            float v = 0.f;
            if (node < NN) {
                if (c < FA) v = x[(size_t)node*FA + c];
                else { int q = c - FA; int g = batch[node]; v = charge[g]*Wc[q] + bc[q]; }
            }
            sX[n*K + c] = v;
        }
        __syncthreads();
        float4 acc[4];
        float4 bb = *(const float4*)&ba[c0];
#pragma unroll
        for (int i = 0; i < 4; ++i) acc[i] = bb;
        mm_tile<108,108>(acc, sX, ng*4, sW, c0);
#pragma unroll
        for (int i = 0; i < 4; ++i) {
            int node = tb + ng*4 + i;
            if (node < NN) *(float4*)&h[(size_t)node*64 + c0] = acc[i];
        }
    }
}

// ---------- edge embedding: ea = edge_attr @ W_bond + b_bond ----------
__global__ __launch_bounds__(256) void embed_edge_kernel(
    const float* __restrict__ eattr, const float* __restrict__ Wb,
    const float* __restrict__ bbond, float* __restrict__ ea)
{
    const int K = 44; // 41 padded to 44
    __shared__ float sW[44*64];
    __shared__ float sX[64*44];
    for (int i = threadIdx.x; i < K*64; i += 256) {
        int r = i >> 6, c = i & 63;
        sW[i] = (r < FB) ? Wb[r*64 + c] : 0.f;
    }
    const int fg = threadIdx.x & 15, ng = threadIdx.x >> 4, c0 = fg*4;
    for (int tb = blockIdx.x*64; tb < EE; tb += gridDim.x*64) {
        __syncthreads();
        for (int i = threadIdx.x; i < 64*K; i += 256) {
            int n = i / K, c = i % K;
            int e = tb + n;
            float v = 0.f;
            if (e < EE && c < FB) v = eattr[(size_t)e*FB + c];
            sX[n*K + c] = v;
        }
        __syncthreads();
        float4 acc[4];
        float4 bv = *(const float4*)&bbond[c0];
#pragma unroll
        for (int i = 0; i < 4; ++i) acc[i] = bv;
        mm_tile<44,44>(acc, sX, ng*4, sW, c0);
#pragma unroll
        for (int i = 0; i < 4; ++i) {
            int e = tb + ng*4 + i;
            if (e < EE) *(float4*)&ea[(size_t)e*64 + c0] = acc[i];
        }
    }
}

// ---------- per-layer node precompute: P1=h@euW1[0:64]+eb1, P2=h@euW1[64:128], P3=h@nuW1[0:64]+nb1 ----------
__global__ __launch_bounds__(256) void precompute_kernel(
    const float* __restrict__ h,
    const float* __restrict__ W1, const float* __restrict__ W2, const float* __restrict__ W3,
    const float* __restrict__ b1, const float* __restrict__ b3,
    float* __restrict__ P1, float* __restrict__ P2, float* __restrict__ P3)
{
    __shared__ float sW1[4096], sW2[4096], sW3[4096];
    __shared__ float sH[64*68];
    for (int i = threadIdx.x; i < 4096; i += 256) { sW1[i]=W1[i]; sW2[i]=W2[i]; sW3[i]=W3[i]; }
    const int fg = threadIdx.x & 15, ng = threadIdx.x >> 4, c0 = fg*4;
    for (int tb = blockIdx.x*64; tb < NN; tb += gridDim.x*64) {
        __syncthreads();
        for (int i = threadIdx.x; i < 4096; i += 256) {
            int n = i >> 6, c = i & 63;
            int node = tb + n;
            sH[n*68 + c] = (node < NN) ? h[(size_t)node*64 + c] : 0.f;
        }
        __syncthreads();
        float4 a1[4], a2[4], a3[4];
        float4 v1 = *(const float4*)&b1[c0];
        float4 v3 = *(const float4*)&b3[c0];
#pragma unroll
        for (int i = 0; i < 4; ++i) { a1[i]=v1; a2[i]=make_float4(0,0,0,0); a3[i]=v3; }
        mm_tile<64,68>(a1, sH, ng*4, sW1, c0);
        mm_tile<64,68>(a2, sH, ng*4, sW2, c0);
        mm_tile<64,68>(a3, sH, ng*4, sW3, c0);
#pragma unroll
        for (int i = 0; i < 4; ++i) {
            int node = tb + ng*4 + i;
            if (node < NN) {
                *(float4*)&P1[(size_t)node*64+c0] = a1[i];
                *(float4*)&P2[(size_t)node*64+c0] = a2[i];
                *(float4*)&P3[(size_t)node*64+c0] = a3[i];
            }
        }
    }
}

// ---------- the big fused per-edge kernel ----------
// t1  = sp(P1[row] + P2[col] + ea@WA)        (WA = eu_W1[128:192])
// ea' = t1@WB + eb2                          (WB = eu_W2)         -> stored
// t2  = sp(P3[row] + ea'@WC)                 (WC = nu_W1[64:128])
// msg = t2@WD + nb2                          (WD = nu_W2)         -> atomically scattered to h_new[col]
__global__ __launch_bounds__(512, 2) void layer_edge_kernel(
    float* __restrict__ ea,
    const float* __restrict__ P1, const float* __restrict__ P2, const float* __restrict__ P3,
    float* __restrict__ h_new,
    const int* __restrict__ rowi, const int* __restrict__ coli,
    const float* __restrict__ WA, const float* __restrict__ WB,
    const float* __restrict__ WC, const float* __restrict__ WD,
    const float* __restrict__ eb2, const float* __restrict__ nb2)
{
    __shared__ float sWA[4096], sWB[4096], sWC[4096], sWD[4096];
    __shared__ float sU[8][16*68];
    __shared__ float sT[8][16*68];
    for (int i = threadIdx.x; i < 4096; i += 512) {
        sWA[i]=WA[i]; sWB[i]=WB[i]; sWC[i]=WC[i]; sWD[i]=WD[i];
    }
    __syncthreads();  // only block-wide sync; after this each wave is independent
    const int wave = threadIdx.x >> 6;
    const int lane = threadIdx.x & 63;
    const int fg = lane & 15, eg = lane >> 4, c0 = fg*4;
    float* U = sU[wave];
    float* T = sT[wave];
    const int numTiles = EE >> 4;   // E divisible by 16
    for (int tile = blockIdx.x*8 + wave; tile < numTiles; tile += gridDim.x*8) {
        const int base = tile << 4;
        int rid[4], cid[4];
#pragma unroll
        for (int i = 0; i < 4; ++i) {
            int e = base + eg*4 + i;
            rid[i] = rowi[e]; cid[i] = coli[e];
        }
        // prefetch node-side gathers (L2/L3-resident)
        float4 g1[4], g2[4], g3[4];
#pragma unroll
        for (int i = 0; i < 4; ++i) {
            g1[i] = *(const float4*)&P1[(size_t)rid[i]*64 + c0];
            g2[i] = *(const float4*)&P2[(size_t)cid[i]*64 + c0];
            g3[i] = *(const float4*)&P3[(size_t)rid[i]*64 + c0];
        }
        // stage ea tile into U (wave-private, ld=68)
#pragma unroll
        for (int j = 0; j < 4; ++j) {
            int i = lane + 64*j;
            int r = i >> 4, cc = (i & 15) << 2;
            float4 v = *(const float4*)&ea[(size_t)(base+r)*64 + cc];
            *(float4*)&U[r*68 + cc] = v;
        }
        __builtin_amdgcn_wave_barrier();
        // phase 1
        float4 acc[4];
#pragma unroll
        for (int i = 0; i < 4; ++i)
            acc[i] = make_float4(g1[i].x+g2[i].x, g1[i].y+g2[i].y, g1[i].z+g2[i].z, g1[i].w+g2[i].w);
        mm_tile<64,68>(acc, U, eg*4, sWA, c0);
#pragma unroll
        for (int i = 0; i < 4; ++i) *(float4*)&T[(eg*4+i)*68 + c0] = sp4(acc[i]);
        __builtin_amdgcn_wave_barrier();
        // phase 2
        float4 bv = *(const float4*)&eb2[c0];
#pragma unroll
        for (int i = 0; i < 4; ++i) acc[i] = bv;
        mm_tile<64,68>(acc, T, eg*4, sWB, c0);
#pragma unroll
        for (int i = 0; i < 4; ++i) {
            int er = eg*4 + i;
            *(float4*)&ea[(size_t)(base+er)*64 + c0] = acc[i];
            *(float4*)&U[er*68 + c0] = acc[i];
        }
        __builtin_amdgcn_wave_barrier();
        // phase 3
#pragma unroll
        for (int i = 0; i < 4; ++i) acc[i] = g3[i];
        mm_tile<64,68>(acc, U, eg*4, sWC, c0);
#pragma unroll
        for (int i = 0; i < 4; ++i) *(float4*)&T[(eg*4+i)*68 + c0] = sp4(acc[i]);
        __builtin_amdgcn_wave_barrier();
        // phase 4
        float4 nv = *(const float4*)&nb2[c0];
#pragma unroll
        for (int i = 0; i < 4; ++i) acc[i] = nv;
        mm_tile<64,68>(acc, T, eg*4, sWD, c0);
#pragma unroll
        for (int i = 0; i < 4; ++i) {
            float* dst = &h_new[(size_t)cid[i]*64 + c0];
            atomAddF(dst+0, acc[i].x);
            atomAddF(dst+1, acc[i].y);
            atomAddF(dst+2, acc[i].z);
            atomAddF(dst+3, acc[i].w);
        }
        __builtin_amdgcn_wave_barrier();
    }
}

// ---------- batchnorm statistics ----------
__global__ __launch_bounds__(256) void bn_stat_kernel(const float* __restrict__ hn, float* __restrict__ stats)
{
    const int col = threadIdx.x & 63, rg = threadIdx.x >> 6;
    float s = 0.f, ss = 0.f;
    for (int n = blockIdx.x*4 + rg; n < NN; n += gridDim.x*4) {
        float v = hn[(size_t)n*64 + col];
        s += v; ss += v*v;
    }
    __shared__ float Ss[4][64], Sq[4][64];
    Ss[rg][col] = s; Sq[rg][col] = ss;
    __syncthreads();
    if (threadIdx.x < 64) {
        float a = Ss[0][col]+Ss[1][col]+Ss[2][col]+Ss[3][col];
        float b = Sq[0][col]+Sq[1][col]+Sq[2][col]+Sq[3][col];
        atomAddF(&stats[col], a);
        atomAddF(&stats[64+col], b);
    }
}

// ---------- bn apply + softplus + residual: h = sp(bn(h_new)) + h ----------
__global__ __launch_bounds__(256) void bn_apply_kernel(
    const float* __restrict__ hn, float* __restrict__ h,
    const float* __restrict__ stats, const float* __restrict__ gamma, const float* __restrict__ beta)
{
    size_t idx = (size_t)blockIdx.x*256 + threadIdx.x;
    if (idx >= (size_t)NN*16) return;
    int c0 = (int)(idx & 15) << 2;
    float4 v = ((const float4*)hn)[idx];
    float4 r = ((const float4*)h)[idx];
    float vv[4] = {v.x, v.y, v.z, v.w};
    float rr[4] = {r.x, r.y, r.z, r.w};
    float oo[4];
    const float invN = 1.0f / (float)NN;
#pragma unroll
    for (int c = 0; c < 4; ++c) {
        int col = c0 + c;
        float mu  = stats[col] * invN;
        float var = stats[64+col] * invN - mu*mu;
        float is  = rsqrtf(var + EPSBN);
        float nv  = (vv[c] - mu) * is * gamma[col] + beta[col];
        oo[c] = sp1(nv) + rr[c];
    }
    ((float4*)h)[idx] = make_float4(oo[0], oo[1], oo[2], oo[3]);
}

// ---------- global mean pool (sums + counts via atomics) ----------
__global__ __launch_bounds__(256) void pool_kernel(
    const float* __restrict__ h, const int* __restrict__ batch,
    float* __restrict__ gsum, float* __restrict__ gcnt)
{
    for (size_t idx = (size_t)blockIdx.x*256 + threadIdx.x; idx < (size_t)NN*64;
         idx += (size_t)gridDim.x*256) {
        int n = (int)(idx >> 6), d = (int)(idx & 63);
        int g = batch[n];
        atomAddF(&gsum[g*64 + d], h[idx]);
        if (d == 0) atomAddF(&gcnt[g], 1.0f);
    }
}

// ---------- predictor MLP: one block per graph ----------
__global__ __launch_bounds__(128) void predictor_kernel(
    const float* __restrict__ gsum, const float* __restrict__ gcnt,
    const float* __restrict__ W1, const float* __restrict__ b1,
    const float* __restrict__ W2, const float* __restrict__ b2,
    const float* __restrict__ W3, const float* __restrict__ b3,
    float* __restrict__ out)
{
    int g = blockIdx.x, t = threadIdx.x;
    __shared__ float gr[64];
    __shared__ float z1[128];
    __shared__ float z2[128];
    __shared__ float red[128];
    if (t < 64) gr[t] = gsum[g*64 + t] / fmaxf(gcnt[g], 1.0f);
    __syncthreads();
    float s = b1[t];
    for (int k = 0; k < 64; ++k) s += gr[k] * W1[k*128 + t];
    z1[t] = sp1(s);
    __syncthreads();
    s = b2[t];
    for (int k = 0; k < 128; ++k) s += z1[k] * W2[k*128 + t];
    z2[t] = sp1(s);
    __syncthreads();
    red[t] = z2[t] * W3[t];
    __syncthreads();
    for (int off = 64; off > 0; off >>= 1) {
        if (t < off) red[t] += red[t + off];
        __syncthreads();
    }
    if (t == 0) out[g] = red[0] + b3[0];
}

// ---------- launch ----------
extern "C" void kernel_launch(void* const* d_in, const int* in_sizes, int n_in,
                              void* d_out, int out_size, void* d_ws, size_t ws_size,
                              hipStream_t stream)
{
    const float* x         = (const float*)d_in[0];
    const float* edge_attr = (const float*)d_in[1];
    const float* charge    = (const float*)d_in[2];
    const int*   edge_index= (const int*)d_in[3];
    const int*   batch     = (const int*)d_in[4];
    const float* W_charge  = (const float*)d_in[5];
    const float* b_charge  = (const float*)d_in[6];
    const float* W_atom    = (const float*)d_in[7];
    const float* b_atom    = (const float*)d_in[8];
    const float* W_bond    = (const float*)d_in[9];
    const float* b_bond    = (const float*)d_in[10];
    const float* nu_W1     = (const float*)d_in[11];
    const float* nu_b1     = (const float*)d_in[12];
    const float* nu_W2     = (const float*)d_in[13];
    const float* nu_b2     = (const float*)d_in[14];
    const float* eu_W1     = (const float*)d_in[15];
    const float* eu_b1     = (const float*)d_in[16];
    const float* eu_W2     = (const float*)d_in[17];
    const float* eu_b2     = (const float*)d_in[18];
    const float* bn_gamma  = (const float*)d_in[19];
    const float* bn_beta   = (const float*)d_in[20];
    const float* p_W1      = (const float*)d_in[21];
    const float* p_b1      = (const float*)d_in[22];
    const float* p_W2      = (const float*)d_in[23];
    const float* p_b2      = (const float*)d_in[24];
    const float* p_W3      = (const float*)d_in[25];
    const float* p_b3      = (const float*)d_in[26];

    const int* rowi = edge_index;
    const int* coli = edge_index + EE;

    char* ws = (char*)d_ws;
    float* ea    = (float*)ws;                 ws += (size_t)EE*64*4;
    float* h     = (float*)ws;                 ws += (size_t)NN*64*4;
    float* P1    = (float*)ws;                 ws += (size_t)NN*64*4;
    float* P2    = (float*)ws;                 ws += (size_t)NN*64*4;
    float* P3    = (float*)ws;                 ws += (size_t)NN*64*4;
    float* h_new = (float*)ws;                 ws += (size_t)NN*64*4;
    float* gsum  = (float*)ws;                 ws += (size_t)GG*64*4;
    float* gcnt  = (float*)ws;                 ws += (size_t)GG*4;
    float* stats = (float*)ws;                 ws += 128*4;

    float* out = (float*)d_out;

    embed_node_kernel<<<512, 256, 0, stream>>>(x, batch, charge, W_charge, b_charge, W_atom, b_atom, h);
    embed_edge_kernel<<<1024, 256, 0, stream>>>(edge_attr, W_bond, b_bond, ea);
    hipMemsetAsync(gsum, 0, (size_t)(GG*64 + GG)*4, stream);

    for (int l = 0; l < NL; ++l) {
        const float* euW1 = eu_W1 + (size_t)l*192*64;
        const float* nuW1 = nu_W1 + (size_t)l*128*64;
        precompute_kernel<<<512, 256, 0, stream>>>(
            h, euW1, euW1 + 64*64, nuW1,
            eu_b1 + l*64, nu_b1 + l*64, P1, P2, P3);
        hipMemsetAsync(h_new, 0, (size_t)NN*64*4, stream);
        hipMemsetAsync(stats, 0, 128*4, stream);
        layer_edge_kernel<<<256, 512, 0, stream>>>(
            ea, P1, P2, P3, h_new, rowi, coli,
            euW1 + 128*64, eu_W2 + (size_t)l*64*64,
            nuW1 + 64*64,  nu_W2 + (size_t)l*64*64,
            eu_b2 + l*64, nu_b2 + l*64);
        bn_stat_kernel<<<256, 256, 0, stream>>>(h_new, stats);
        bn_apply_kernel<<<(NN*16 + 255)/256, 256, 0, stream>>>(
            h_new, h, stats, bn_gamma + l*64, bn_beta + l*64);
    }

    pool_kernel<<<2048, 256, 0, stream>>>(h, batch, gsum, gcnt);
    predictor_kernel<<<GG, 128, 0, stream>>>(gsum, gcnt, p_W1, p_b1, p_W2, p_b2, p_W3, p_b3, out);
}